// Round 2
// baseline (5153.320 us; speedup 1.0000x reference)
//
#include <hip/hip_runtime.h>
#include <hip/hip_bf16.h>

#define DD 32
#define GG 96   // 3*DD
#define NP 16   // paths per readout block

__device__ __forceinline__ float frcp(float x){
#if defined(__has_builtin)
#if __has_builtin(__builtin_amdgcn_rcpf)
    return __builtin_amdgcn_rcpf(x);
#else
    return 1.0f / x;
#endif
#else
    return 1.0f / x;
#endif
}

__device__ __forceinline__ float fsig(float x){
    float e = __expf(-x);                 // x<<0 -> e=inf -> rcp(inf)=0  (correct)
    return frcp(1.0f + e);
}
__device__ __forceinline__ float ftanh(float x){
    float ax = fabsf(x);
    float e  = __expf(-2.0f * ax);        // in (0,1], no overflow
    float t  = (1.0f - e) * frcp(1.0f + e);
    return copysignf(t, x);
}

// ---------------- setup kernels ----------------

__global__ void zero_ints_kernel(int* a, int n){
    int i = blockIdx.x * blockDim.x + threadIdx.x;
    if (i < n) a[i] = 0;
}

__global__ void init_link_kernel(const float* __restrict__ cap, float* __restrict__ ls, int n_links){
    int i = blockIdx.x * blockDim.x + threadIdx.x;
    if (i >= n_links * DD) return;
    int l = i >> 5, d = i & 31;
    ls[i] = (d == 0) ? cap[l] : 0.0f;
}

__global__ void init_path_kernel(const float* __restrict__ traffic, const float* __restrict__ packets,
                                 const float* __restrict__ tdp, float* __restrict__ ps, int n_paths){
    int i = blockIdx.x * blockDim.x + threadIdx.x;
    if (i >= n_paths * DD) return;
    int p = i >> 5, d = i & 31;
    float v = 0.0f;
    if (d == 0) v = traffic[p];
    else if (d == 1) v = packets[p];
    else if (d < 14) v = tdp[p * 12 + (d - 2)];
    ps[i] = v;
}

// per-path start/len (edges of a path are contiguous & ordered), link incidence counts
__global__ void meta_kernel(const int* __restrict__ path_ids, const int* __restrict__ seqp,
                            const int* __restrict__ seql, int* __restrict__ start,
                            int* __restrict__ lenp, int* __restrict__ lcount, int E){
    int e = blockIdx.x * blockDim.x + threadIdx.x;
    if (e >= E) return;
    int p = path_ids[e];
    int s = seqp[e];
    if (s == 0) start[p] = e;
    if (e == E - 1 || path_ids[e + 1] != p) lenp[p] = s + 1;
    atomicAdd(&lcount[seql[e]], 1);
}

__global__ void bhist_kernel(const int* __restrict__ lenp, int* __restrict__ bcnt, int n_paths){
    int p = blockIdx.x * blockDim.x + threadIdx.x;
    if (p >= n_paths) return;
    atomicAdd(&bcnt[lenp[p] - 1], 1);
}

__global__ void bscan_kernel(const int* __restrict__ bcnt, int* __restrict__ bbase){
    if (threadIdx.x == 0 && blockIdx.x == 0){
        int run = 0;
        for (int i = 0; i < 16; i++){ bbase[i] = run; run += bcnt[i]; }
    }
}

__global__ void bscatter_kernel(const int* __restrict__ lenp, const int* __restrict__ bbase,
                                int* __restrict__ bfill, int* __restrict__ order, int n_paths){
    int p = blockIdx.x * blockDim.x + threadIdx.x;
    if (p >= n_paths) return;
    int b = lenp[p] - 1;
    int pos = bbase[b] + atomicAdd(&bfill[b], 1);
    order[pos] = p;
}

// exclusive scan of n counts -> off[0..n]  (single block, 1024 threads)
__global__ __launch_bounds__(1024) void scan_kernel(const int* __restrict__ cnt, int* __restrict__ off, int n){
    __shared__ int psh[1025];
    int tid = threadIdx.x;
    int chunk = (n + 1023) / 1024;
    int b = tid * chunk, e = min(b + chunk, n);
    int s = 0;
    for (int i = b; i < e; ++i) s += cnt[i];
    psh[tid + 1] = s;
    if (tid == 0) psh[0] = 0;
    __syncthreads();
    for (int ofs = 1; ofs < 1024; ofs <<= 1){
        int v = (tid + 1 >= ofs) ? psh[tid + 1 - ofs] : 0;
        __syncthreads();
        psh[tid + 1] += v;
        __syncthreads();
    }
    int run = psh[tid];
    for (int i = b; i < e; ++i){ off[i] = run; run += cnt[i]; }
    if (b < n && e == n) off[n] = run;
}

__global__ void fillpbl_kernel(const int* __restrict__ seql, const int* __restrict__ p2l,
                               const int* __restrict__ loff, int* __restrict__ lfill,
                               int* __restrict__ pbl, int E){
    int e = blockIdx.x * blockDim.x + threadIdx.x;
    if (e >= E) return;
    int l = seql[e];
    int pos = loff[l] + atomicAdd(&lfill[l], 1);
    pbl[pos] = p2l[e];
}

// ---------------- GRU core (shared by path & link kernels) ----------------
// xs4/hs4: [8][NT] float4 LDS columns (per-thread x,h).
// Weights read DIRECTLY from global with wave-uniform addresses -> s_load
// (scalar pipe, broadcast, parallel to VALU). No LDS staging, no barrier.
template<int NT>
__device__ __forceinline__ void gru_step(const float* __restrict__ K, const float* __restrict__ RK,
                                         const float* __restrict__ bias,
                                         float4* xs4, float4* hs4, int tid)
{
    float az[DD], ar[DD], axh[DD], ahh[DD];
    #pragma unroll
    for (int j = 0; j < DD; j++){
        az[j]  = bias[j]          + bias[GG + j];
        ar[j]  = bias[DD + j]     + bias[GG + DD + j];
        axh[j] = bias[2*DD + j];
        ahh[j] = bias[GG + 2*DD + j];
    }
    #pragma unroll 1
    for (int k4 = 0; k4 < 8; k4++){
        float4 xv = xs4[k4 * NT + tid];
        float4 hv = hs4[k4 * NT + tid];
        #pragma unroll
        for (int kk = 0; kk < 4; kk++){
            int k = k4 * 4 + kk;
            float xk = ((const float*)&xv)[kk];
            float hk = ((const float*)&hv)[kk];
            const float* krow = K  + k * GG;
            const float* rrow = RK + k * GG;
            #pragma unroll
            for (int j = 0; j < DD; j++){
                az[j]  = fmaf(xk, krow[j],        az[j]);
                az[j]  = fmaf(hk, rrow[j],        az[j]);
                ar[j]  = fmaf(xk, krow[DD + j],   ar[j]);
                ar[j]  = fmaf(hk, rrow[DD + j],   ar[j]);
                axh[j] = fmaf(xk, krow[2*DD + j], axh[j]);
                ahh[j] = fmaf(hk, rrow[2*DD + j], ahh[j]);
            }
        }
    }
    #pragma unroll
    for (int j4 = 0; j4 < 8; j4++){
        float4 hold = hs4[j4 * NT + tid];
        float4 hnew;
        #pragma unroll
        for (int jj = 0; jj < 4; jj++){
            int j = j4 * 4 + jj;
            float z = fsig(az[j]);
            float r = fsig(ar[j]);
            float c = ftanh(axh[j] + r * ahh[j]);
            float hv = ((const float*)&hold)[jj];
            ((float*)&hnew)[jj] = fmaf(z, hv, (1.0f - z) * c);
        }
        hs4[j4 * NT + tid] = hnew;
    }
}

// one path per thread; wave-chunk permutation spreads long-path waves across CUs
__global__ __launch_bounds__(256, 2) void path_gru_kernel(
    const float* __restrict__ ls, float* __restrict__ ps,
    const int* __restrict__ l2p, const int* __restrict__ start,
    const int* __restrict__ lenp, const int* __restrict__ order,
    const float* __restrict__ K, const float* __restrict__ RK,
    const float* __restrict__ bias, int n_paths, int n_chunks, int stride)
{
    __shared__ __align__(16) float4 xs4[8 * 256];
    __shared__ __align__(16) float4 hs4[8 * 256];

    int tid = threadIdx.x;
    int gthread = blockIdx.x * 256 + tid;
    int wave = gthread >> 6;
    if (wave >= n_chunks) return;
    long long ch = ((long long)wave * stride) % n_chunks;
    int idx = (int)ch * 64 + (tid & 63);
    if (idx >= n_paths) return;
    int p = order[idx];

    const float4* hp = (const float4*)(ps + (size_t)p * DD);
    #pragma unroll
    for (int q = 0; q < 8; q++) hs4[q * 256 + tid] = hp[q];

    int s0 = start[p];
    int L  = lenp[p];
    for (int t = 0; t < L; ++t){
        int lk = l2p[s0 + t];
        const float4* xp = (const float4*)(ls + (size_t)lk * DD);
        #pragma unroll
        for (int q = 0; q < 8; q++) xs4[q * 256 + tid] = xp[q];
        gru_step<256>(K, RK, bias, xs4, hs4, tid);
    }
    float4* op = (float4*)(ps + (size_t)p * DD);
    #pragma unroll
    for (int q = 0; q < 8; q++) op[q] = hs4[q * 256 + tid];
}

__global__ __launch_bounds__(256, 2) void link_gru_kernel(
    const float* __restrict__ psum, float* __restrict__ ls,
    const float* __restrict__ K, const float* __restrict__ RK,
    const float* __restrict__ bias, int n_links)
{
    __shared__ __align__(16) float4 xs4[8 * 256];
    __shared__ __align__(16) float4 hs4[8 * 256];

    int tid = threadIdx.x;
    int idx = blockIdx.x * 256 + tid;
    if (idx >= n_links) return;

    const float4* hp = (const float4*)(ls   + (size_t)idx * DD);
    const float4* xp = (const float4*)(psum + (size_t)idx * DD);
    #pragma unroll
    for (int q = 0; q < 8; q++){ hs4[q * 256 + tid] = hp[q]; xs4[q * 256 + tid] = xp[q]; }
    gru_step<256>(K, RK, bias, xs4, hs4, tid);
    float4* op = (float4*)(ls + (size_t)idx * DD);
    #pragma unroll
    for (int q = 0; q < 8; q++) op[q] = hs4[q * 256 + tid];
}

// segment sum: path states -> per-link sums (CSR), thread = (link, dim)
__global__ void psum_kernel(const float* __restrict__ ps, const int* __restrict__ loff,
                            const int* __restrict__ pbl, float* __restrict__ psum, int n_links){
    int i = blockIdx.x * blockDim.x + threadIdx.x;
    if (i >= n_links * DD) return;
    int l = i >> 5, d = i & 31;
    int b = loff[l], e = loff[l + 1];
    float s = 0.0f;
    for (int k = b; k < e; ++k) s += ps[(size_t)pbl[k] * DD + d];
    psum[i] = s;
}

// fused readout MLP: 32 -> 256 relu -> 256 relu -> 1, NP paths per 256-thread block
__global__ __launch_bounds__(256) void readout_kernel(
    const float* __restrict__ ps,
    const float* __restrict__ w1, const float* __restrict__ b1,
    const float* __restrict__ w2, const float* __restrict__ b2,
    const float* __restrict__ w3, const float* __restrict__ b3,
    float* __restrict__ out, int n_paths)
{
    __shared__ __align__(16) float xsh[NP * DD];
    __shared__ __align__(16) float h1[NP * 256];
    __shared__ float wred[4 * NP];
    int j = threadIdx.x;
    int p0 = blockIdx.x * NP;
    for (int i = j; i < NP * DD; i += 256){
        int p = p0 + i / DD;
        xsh[i] = (p < n_paths) ? ps[(size_t)p * DD + (i % DD)] : 0.0f;
    }
    __syncthreads();

    float acc[NP];
    float bj = b1[j];
    #pragma unroll
    for (int p = 0; p < NP; p++) acc[p] = bj;
    const float4* xq = (const float4*)xsh;
    #pragma unroll 1
    for (int k4 = 0; k4 < DD / 4; k4++){
        float wa = w1[(k4 * 4 + 0) * 256 + j];
        float wb = w1[(k4 * 4 + 1) * 256 + j];
        float wc = w1[(k4 * 4 + 2) * 256 + j];
        float wd = w1[(k4 * 4 + 3) * 256 + j];
        #pragma unroll
        for (int p = 0; p < NP; p++){
            float4 hv = xq[p * (DD / 4) + k4];
            acc[p] = fmaf(hv.x, wa, acc[p]);
            acc[p] = fmaf(hv.y, wb, acc[p]);
            acc[p] = fmaf(hv.z, wc, acc[p]);
            acc[p] = fmaf(hv.w, wd, acc[p]);
        }
    }
    #pragma unroll
    for (int p = 0; p < NP; p++) h1[p * 256 + j] = fmaxf(acc[p], 0.0f);
    __syncthreads();

    float b2j = b2[j];
    #pragma unroll
    for (int p = 0; p < NP; p++) acc[p] = b2j;
    const float4* h1q = (const float4*)h1;
    #pragma unroll 1
    for (int k4 = 0; k4 < 64; k4++){
        float wa = w2[(k4 * 4 + 0) * 256 + j];
        float wb = w2[(k4 * 4 + 1) * 256 + j];
        float wc = w2[(k4 * 4 + 2) * 256 + j];
        float wd = w2[(k4 * 4 + 3) * 256 + j];
        #pragma unroll
        for (int p = 0; p < NP; p++){
            float4 hv = h1q[p * 64 + k4];
            acc[p] = fmaf(hv.x, wa, acc[p]);
            acc[p] = fmaf(hv.y, wb, acc[p]);
            acc[p] = fmaf(hv.z, wc, acc[p]);
            acc[p] = fmaf(hv.w, wd, acc[p]);
        }
    }

    float w3j = w3[j];
    int lane = j & 63, wid = j >> 6;
    #pragma unroll
    for (int p = 0; p < NP; p++){
        float v = fmaxf(acc[p], 0.0f) * w3j;
        v += __shfl_down(v, 32);
        v += __shfl_down(v, 16);
        v += __shfl_down(v, 8);
        v += __shfl_down(v, 4);
        v += __shfl_down(v, 2);
        v += __shfl_down(v, 1);
        if (lane == 0) wred[wid * NP + p] = v;
    }
    __syncthreads();
    if (j < NP){
        int p = p0 + j;
        if (p < n_paths){
            float v = wred[j] + wred[NP + j] + wred[2 * NP + j] + wred[3 * NP + j] + b3[0];
            out[p] = v;
        }
    }
}

static int host_gcd(int a, int b){ while (b){ int t = a % b; a = b; b = t; } return a; }

extern "C" void kernel_launch(void* const* d_in, const int* in_sizes, int n_in,
                              void* d_out, int out_size, void* d_ws, size_t ws_size,
                              hipStream_t stream)
{
    const float* capacity = (const float*)d_in[0];
    const float* traffic  = (const float*)d_in[1];
    const float* packets  = (const float*)d_in[2];
    const float* tdp      = (const float*)d_in[3];
    const float* pK  = (const float*)d_in[4];
    const float* pRK = (const float*)d_in[5];
    const float* pB  = (const float*)d_in[6];
    const float* lK  = (const float*)d_in[7];
    const float* lRK = (const float*)d_in[8];
    const float* lB  = (const float*)d_in[9];
    const float* w1  = (const float*)d_in[10];
    const float* b1  = (const float*)d_in[11];
    const float* w2  = (const float*)d_in[12];
    const float* b2  = (const float*)d_in[13];
    const float* w3  = (const float*)d_in[14];
    const float* b3  = (const float*)d_in[15];
    const int* l2p      = (const int*)d_in[16];
    const int* path_ids = (const int*)d_in[17];
    const int* seqp     = (const int*)d_in[18];
    const int* p2l      = (const int*)d_in[19];
    const int* seql     = (const int*)d_in[20];
    int n_links = in_sizes[0];
    int n_paths = in_sizes[1];
    int E       = in_sizes[16];
    float* out = (float*)d_out;

    char* w = (char*)d_ws;
    auto carve = [&](size_t bytes) -> void* {
        void* r = (void*)w;
        w += (bytes + 255) & ~(size_t)255;
        return r;
    };
    float* ls   = (float*)carve((size_t)n_links * DD * 4);
    float* ps   = (float*)carve((size_t)n_paths * DD * 4);
    float* psum = (float*)carve((size_t)n_links * DD * 4);
    int* start  = (int*)carve((size_t)n_paths * 4);
    int* lenp   = (int*)carve((size_t)n_paths * 4);
    int* order  = (int*)carve((size_t)n_paths * 4);
    int* loff   = (int*)carve((size_t)(n_links + 1) * 4);
    int* pbl    = (int*)carve((size_t)E * 4);
    int* izero  = (int*)carve(((size_t)2 * n_links + 48) * 4);
    int* lcount = izero;
    int* lfill  = izero + n_links;
    int* bcnt   = izero + 2 * n_links;
    int* bfill  = izero + 2 * n_links + 16;
    int* bbase  = izero + 2 * n_links + 32;

    const int TB = 256;
    int nz = 2 * n_links + 48;
    zero_ints_kernel<<<(nz + TB - 1) / TB, TB, 0, stream>>>(izero, nz);
    init_link_kernel<<<(n_links * DD + TB - 1) / TB, TB, 0, stream>>>(capacity, ls, n_links);
    init_path_kernel<<<(n_paths * DD + TB - 1) / TB, TB, 0, stream>>>(traffic, packets, tdp, ps, n_paths);
    meta_kernel<<<(E + TB - 1) / TB, TB, 0, stream>>>(path_ids, seqp, seql, start, lenp, lcount, E);
    bhist_kernel<<<(n_paths + TB - 1) / TB, TB, 0, stream>>>(lenp, bcnt, n_paths);
    bscan_kernel<<<1, 64, 0, stream>>>(bcnt, bbase);
    bscatter_kernel<<<(n_paths + TB - 1) / TB, TB, 0, stream>>>(lenp, bbase, bfill, order, n_paths);
    scan_kernel<<<1, 1024, 0, stream>>>(lcount, loff, n_links);
    fillpbl_kernel<<<(E + TB - 1) / TB, TB, 0, stream>>>(seql, p2l, loff, lfill, pbl, E);

    int n_chunks = (n_paths + 63) / 64;
    int stride = 1;
    if (n_chunks > 2){
        stride = (int)((double)n_chunks * 0.381966);
        if (stride < 1) stride = 1;
        while (host_gcd(stride, n_chunks) != 1) stride++;
    }
    int pg_blocks = (n_chunks * 64 + 255) / 256;

    for (int it = 0; it < 8; ++it){
        path_gru_kernel<<<pg_blocks, 256, 0, stream>>>(ls, ps, l2p, start, lenp, order,
                                                       pK, pRK, pB, n_paths, n_chunks, stride);
        psum_kernel<<<(n_links * DD + TB - 1) / TB, TB, 0, stream>>>(ps, loff, pbl, psum, n_links);
        link_gru_kernel<<<(n_links + 255) / 256, 256, 0, stream>>>(psum, ls, lK, lRK, lB, n_links);
    }
    readout_kernel<<<(n_paths + NP - 1) / NP, 256, 0, stream>>>(ps, w1, b1, w2, b2, w3, b3, out, n_paths);
}

// Round 4
// 2038.612 us; speedup vs baseline: 2.5279x; 2.5279x over previous
//
#include <hip/hip_runtime.h>
#include <hip/hip_bf16.h>

#define DD 32
#define GG 96   // 3*DD
#define NP 16   // paths per readout block

typedef __attribute__((ext_vector_type(8))) short bf16x8;
typedef __attribute__((ext_vector_type(4))) float f32x4;

__device__ __forceinline__ float frcp(float x){ return __builtin_amdgcn_rcpf(x); }
__device__ __forceinline__ float fsig(float x){
    float e = __expf(-x);
    return frcp(1.0f + e);
}
__device__ __forceinline__ float ftanh(float x){
    float ax = fabsf(x);
    float e  = __expf(-2.0f * ax);
    float t  = (1.0f - e) * frcp(1.0f + e);
    return copysignf(t, x);
}
__device__ __forceinline__ short f2bf(float f){
    union { float f; unsigned u; } v; v.f = f;
    unsigned r = v.u + 0x7fffu + ((v.u >> 16) & 1u);   // RNE
    return (short)(r >> 16);
}
__device__ __forceinline__ float bf2f(short s){
    union { unsigned u; float f; } v; v.u = ((unsigned)(unsigned short)s) << 16;
    return v.f;
}
__device__ __forceinline__ void split2(float x, short& hi, short& lo){
    hi = f2bf(x);
    lo = f2bf(x - bf2f(hi));
}
__device__ __forceinline__ f32x4 splat4(float x){ f32x4 v = { x, x, x, x }; return v; }

// ---------------- setup kernels ----------------

__global__ void zero_ints_kernel(int* a, int n){
    int i = blockIdx.x * blockDim.x + threadIdx.x;
    if (i < n) a[i] = 0;
}

__global__ void init_link_kernel(const float* __restrict__ cap, float* __restrict__ ls,
                                 short* __restrict__ lsbh, short* __restrict__ lsbl, int n_links){
    int i = blockIdx.x * blockDim.x + threadIdx.x;
    if (i >= n_links * DD) return;
    int l = i >> 5, d = i & 31;
    float v = (d == 0) ? cap[l] : 0.0f;
    ls[i] = v;
    short hi, lo; split2(v, hi, lo);
    lsbh[i] = hi; lsbl[i] = lo;
}

__global__ void init_path_kernel(const float* __restrict__ traffic, const float* __restrict__ packets,
                                 const float* __restrict__ tdp, float* __restrict__ ps, int n_paths){
    int i = blockIdx.x * blockDim.x + threadIdx.x;
    if (i >= n_paths * DD) return;
    int p = i >> 5, d = i & 31;
    float v = 0.0f;
    if (d == 0) v = traffic[p];
    else if (d == 1) v = packets[p];
    else if (d < 14) v = tdp[p * 12 + (d - 2)];
    ps[i] = v;
}

__global__ void meta_kernel(const int* __restrict__ path_ids, const int* __restrict__ seqp,
                            const int* __restrict__ seql, int* __restrict__ start,
                            int* __restrict__ lenp, int* __restrict__ lcount, int E){
    int e = blockIdx.x * blockDim.x + threadIdx.x;
    if (e >= E) return;
    int p = path_ids[e];
    int s = seqp[e];
    if (s == 0) start[p] = e;
    if (e == E - 1 || path_ids[e + 1] != p) lenp[p] = s + 1;
    atomicAdd(&lcount[seql[e]], 1);
}

__global__ void bhist_kernel(const int* __restrict__ lenp, int* __restrict__ bcnt, int n_paths){
    int p = blockIdx.x * blockDim.x + threadIdx.x;
    if (p >= n_paths) return;
    atomicAdd(&bcnt[lenp[p] - 1], 1);
}

__global__ void bscan_kernel(const int* __restrict__ bcnt, int* __restrict__ bbase){
    if (threadIdx.x == 0 && blockIdx.x == 0){
        int run = 0;
        for (int i = 0; i < 16; i++){ bbase[i] = run; run += bcnt[i]; }
    }
}

__global__ void bscatter_kernel(const int* __restrict__ lenp, const int* __restrict__ bbase,
                                int* __restrict__ bfill, int* __restrict__ order, int n_paths){
    int p = blockIdx.x * blockDim.x + threadIdx.x;
    if (p >= n_paths) return;
    int b = lenp[p] - 1;
    int pos = bbase[b] + atomicAdd(&bfill[b], 1);
    order[pos] = p;
}

__global__ __launch_bounds__(1024) void scan_kernel(const int* __restrict__ cnt, int* __restrict__ off, int n){
    __shared__ int psh[1025];
    int tid = threadIdx.x;
    int chunk = (n + 1023) / 1024;
    int b = tid * chunk, e = min(b + chunk, n);
    int s = 0;
    for (int i = b; i < e; ++i) s += cnt[i];
    psh[tid + 1] = s;
    if (tid == 0) psh[0] = 0;
    __syncthreads();
    for (int ofs = 1; ofs < 1024; ofs <<= 1){
        int v = (tid + 1 >= ofs) ? psh[tid + 1 - ofs] : 0;
        __syncthreads();
        psh[tid + 1] += v;
        __syncthreads();
    }
    int run = psh[tid];
    for (int i = b; i < e; ++i){ off[i] = run; run += cnt[i]; }
    if (b < n && e == n) off[n] = run;
}

__global__ void fillpbl_kernel(const int* __restrict__ seql, const int* __restrict__ p2l,
                               const int* __restrict__ loff, int* __restrict__ lfill,
                               int* __restrict__ pbl, int E){
    int e = blockIdx.x * blockDim.x + threadIdx.x;
    if (e >= E) return;
    int l = seql[e];
    int pos = loff[l] + atomicAdd(&lfill[l], 1);
    pbl[pos] = p2l[e];
}

// ---------------- MFMA GRU helpers ----------------
// B-fragment (hi/lo split) of weight tile jt (cols jt*16..+16) of W[32][96]:
// lane: n = lane&15 (col), k = (lane>>4)*8 + i
__device__ __forceinline__ void load_wfrag2(const float* __restrict__ W, int n, int g, int jt,
                                            bf16x8& h, bf16x8& l){
    #pragma unroll
    for (int i = 0; i < 8; i++){
        float w = W[(g * 8 + i) * GG + jt * 16 + n];
        short hi, lo; split2(w, hi, lo);
        h[i] = hi; l[i] = lo;
    }
}

#define MFMA3(acc, ah, al, bh, bl) do { \
    acc = __builtin_amdgcn_mfma_f32_16x16x32_bf16(ah, bh, acc, 0, 0, 0); \
    acc = __builtin_amdgcn_mfma_f32_16x16x32_bf16(al, bh, acc, 0, 0, 0); \
    acc = __builtin_amdgcn_mfma_f32_16x16x32_bf16(ah, bl, acc, 0, 0, 0); \
} while (0)

// gates in D-layout: lane col n=lane&15 (dim within 16-tile), rows = 4 paths (g*4+r).
// accZR tiles 0..3: {0,1}=xz+hz+biases, {2,3}=xr+hr+biases. accXC/accHC: xh / hh tiles.
template<bool MASK>
__device__ __forceinline__ void gru_gates(const f32x4 accZR[4], const f32x4 accXC[2], const f32x4 accHC[2],
                                          float hD[2][4], const int lenD[4], int t)
{
    #pragma unroll
    for (int tt = 0; tt < 2; tt++){
        #pragma unroll
        for (int r = 0; r < 4; r++){
            float z = fsig(accZR[tt][r]);
            float rr = fsig(accZR[2 + tt][r]);
            float c = ftanh(accXC[tt][r] + rr * accHC[tt][r]);
            float hn = z * hD[tt][r] + (1.0f - z) * c;
            if (MASK) hD[tt][r] = (t < lenD[r]) ? hn : hD[tt][r];
            else      hD[tt][r] = hn;
        }
    }
}

// ---------------- path GRU (MFMA split-bf16, 16 paths/wave) ----------------
__global__ __launch_bounds__(256, 2) void path_gru_kernel(
    const short* __restrict__ lsbh, const short* __restrict__ lsbl, float* __restrict__ ps,
    const int* __restrict__ l2p, const int* __restrict__ start,
    const int* __restrict__ lenp, const int* __restrict__ order,
    const float* __restrict__ K, const float* __restrict__ RK,
    const float* __restrict__ bias, int n_paths, int n_waves, int stride)
{
    __shared__ __align__(16) float hlds[4][16 * 36];

    int tid = threadIdx.x;
    int warp = tid >> 6;
    int lane = tid & 63;
    int l15 = lane & 15, g = lane >> 4;

    int w = blockIdx.x * 4 + warp;
    if (w >= n_waves) return;
    long long wp = ((long long)w * stride) % n_waves;
    int base16 = (int)wp * 16;

    // weight fragments (register-resident for the whole launch), hi/lo split
    bf16x8 wKh[6], wKl[6], wRKh[6], wRKl[6];
    #pragma unroll
    for (int jt = 0; jt < 6; jt++){
        load_wfrag2(K,  l15, g, jt, wKh[jt],  wKl[jt]);
        load_wfrag2(RK, l15, g, jt, wRKh[jt], wRKl[jt]);
    }
    float bzr[4], bx2[2], bh2[2];
    #pragma unroll
    for (int jt = 0; jt < 4; jt++) bzr[jt] = bias[jt * 16 + l15] + bias[GG + jt * 16 + l15];
    #pragma unroll
    for (int u = 0; u < 2; u++){
        bx2[u] = bias[(4 + u) * 16 + l15];
        bh2[u] = bias[GG + (4 + u) * 16 + l15];
    }

    // A-side path (row = l15)
    int aidx = base16 + l15;
    int pa = order[min(aidx, n_paths - 1)];
    int s0 = start[pa];
    int la_c = lenp[pa];
    int la = (aidx < n_paths) ? la_c : 0;
    int maxlen = __shfl(la_c, 15);

    // D-side paths (4 rows this lane covers)
    int pD[4], lenD[4]; bool vD[4];
    #pragma unroll
    for (int r = 0; r < 4; r++){
        int di = base16 + g * 4 + r;
        vD[r] = (di < n_paths);
        pD[r] = order[min(di, n_paths - 1)];
        lenD[r] = vD[r] ? lenp[pD[r]] : 0;
    }

    // h state: f32 in D-layout
    float hD[2][4];
    #pragma unroll
    for (int tt = 0; tt < 2; tt++)
        #pragma unroll
        for (int r = 0; r < 4; r++)
            hD[tt][r] = ps[(size_t)pD[r] * DD + l15 + tt * 16];

    // initial h A-fragment (hi/lo) straight from ps
    bf16x8 hfh, hfl;
    {
        const float* hp = ps + (size_t)pa * DD + g * 8;
        #pragma unroll
        for (int i = 0; i < 8; i++){ short hi, lo; split2(hp[i], hi, lo); hfh[i] = hi; hfl[i] = lo; }
    }

    float* hl = hlds[warp];

    for (int t = 0; t < maxlen; ++t){
        // gather x fragment (bf16 hi/lo link state row)
        int e = s0 + max(min(t, la - 1), 0);
        int lk = l2p[e];
        bf16x8 xfh = *reinterpret_cast<const bf16x8*>(lsbh + (size_t)lk * DD + g * 8);
        bf16x8 xfl = *reinterpret_cast<const bf16x8*>(lsbl + (size_t)lk * DD + g * 8);

        f32x4 accZR[4], accXC[2], accHC[2];
        #pragma unroll
        for (int jt = 0; jt < 4; jt++){
            f32x4 a = splat4(bzr[jt]);
            MFMA3(a, xfh, xfl, wKh[jt],  wKl[jt]);
            MFMA3(a, hfh, hfl, wRKh[jt], wRKl[jt]);
            accZR[jt] = a;
        }
        #pragma unroll
        for (int u = 0; u < 2; u++){
            f32x4 ax = splat4(bx2[u]);
            MFMA3(ax, xfh, xfl, wKh[4 + u], wKl[4 + u]);
            accXC[u] = ax;
            f32x4 ah = splat4(bh2[u]);
            MFMA3(ah, hfh, hfl, wRKh[4 + u], wRKl[4 + u]);
            accHC[u] = ah;
        }

        gru_gates<true>(accZR, accXC, accHC, hD, lenD, t);

        // transpose h (D-layout f32) -> A-fragment (hi/lo bf16) via wave-private LDS
        #pragma unroll
        for (int tt = 0; tt < 2; tt++)
            #pragma unroll
            for (int r = 0; r < 4; r++)
                hl[(g * 4 + r) * 36 + l15 + tt * 16] = hD[tt][r];
        const float* hrow = hl + l15 * 36 + g * 8;
        #pragma unroll
        for (int i = 0; i < 8; i++){ short hi, lo; split2(hrow[i], hi, lo); hfh[i] = hi; hfl[i] = lo; }
    }

    // store final h
    #pragma unroll
    for (int r = 0; r < 4; r++){
        if (vD[r]){
            #pragma unroll
            for (int tt = 0; tt < 2; tt++)
                ps[(size_t)pD[r] * DD + l15 + tt * 16] = hD[tt][r];
        }
    }
}

// ---------------- link GRU (MFMA split-bf16, 16 links/wave, single step) ----------------
__global__ __launch_bounds__(256, 2) void link_gru_kernel(
    const float* __restrict__ psum, float* __restrict__ ls,
    short* __restrict__ lsbh, short* __restrict__ lsbl,
    const float* __restrict__ K, const float* __restrict__ RK,
    const float* __restrict__ bias, int n_links)
{
    int tid = threadIdx.x;
    int warp = tid >> 6;
    int lane = tid & 63;
    int l15 = lane & 15, g = lane >> 4;

    int base16 = (blockIdx.x * 4 + warp) * 16;
    if (base16 >= n_links) return;

    bf16x8 wKh[6], wKl[6], wRKh[6], wRKl[6];
    #pragma unroll
    for (int jt = 0; jt < 6; jt++){
        load_wfrag2(K,  l15, g, jt, wKh[jt],  wKl[jt]);
        load_wfrag2(RK, l15, g, jt, wRKh[jt], wRKl[jt]);
    }
    float bzr[4], bx2[2], bh2[2];
    #pragma unroll
    for (int jt = 0; jt < 4; jt++) bzr[jt] = bias[jt * 16 + l15] + bias[GG + jt * 16 + l15];
    #pragma unroll
    for (int u = 0; u < 2; u++){
        bx2[u] = bias[(4 + u) * 16 + l15];
        bh2[u] = bias[GG + (4 + u) * 16 + l15];
    }

    int pa = min(base16 + l15, n_links - 1);

    int pD[4]; bool vD[4]; int lenD[4];
    #pragma unroll
    for (int r = 0; r < 4; r++){
        int di = base16 + g * 4 + r;
        vD[r] = (di < n_links);
        pD[r] = min(di, n_links - 1);
        lenD[r] = 0;
    }

    float hD[2][4];
    #pragma unroll
    for (int tt = 0; tt < 2; tt++)
        #pragma unroll
        for (int r = 0; r < 4; r++)
            hD[tt][r] = ls[(size_t)pD[r] * DD + l15 + tt * 16];

    bf16x8 hfh, hfl, xfh, xfl;
    {
        const float* hp = ls + (size_t)pa * DD + g * 8;
        const float* xp = psum + (size_t)pa * DD + g * 8;
        #pragma unroll
        for (int i = 0; i < 8; i++){
            short hi, lo;
            split2(hp[i], hi, lo); hfh[i] = hi; hfl[i] = lo;
            split2(xp[i], hi, lo); xfh[i] = hi; xfl[i] = lo;
        }
    }

    f32x4 accZR[4], accXC[2], accHC[2];
    #pragma unroll
    for (int jt = 0; jt < 4; jt++){
        f32x4 a = splat4(bzr[jt]);
        MFMA3(a, xfh, xfl, wKh[jt],  wKl[jt]);
        MFMA3(a, hfh, hfl, wRKh[jt], wRKl[jt]);
        accZR[jt] = a;
    }
    #pragma unroll
    for (int u = 0; u < 2; u++){
        f32x4 ax = splat4(bx2[u]);
        MFMA3(ax, xfh, xfl, wKh[4 + u], wKl[4 + u]);
        accXC[u] = ax;
        f32x4 ah = splat4(bh2[u]);
        MFMA3(ah, hfh, hfl, wRKh[4 + u], wRKl[4 + u]);
        accHC[u] = ah;
    }
    gru_gates<false>(accZR, accXC, accHC, hD, lenD, 0);

    #pragma unroll
    for (int r = 0; r < 4; r++){
        if (vD[r]){
            #pragma unroll
            for (int tt = 0; tt < 2; tt++){
                float v = hD[tt][r];
                size_t off = (size_t)pD[r] * DD + l15 + tt * 16;
                ls[off] = v;
                short hi, lo; split2(v, hi, lo);
                lsbh[off] = hi; lsbl[off] = lo;
            }
        }
    }
}

// segment sum: path states -> per-link sums (CSR), thread = (link, dim)
__global__ void psum_kernel(const float* __restrict__ ps, const int* __restrict__ loff,
                            const int* __restrict__ pbl, float* __restrict__ psum, int n_links){
    int i = blockIdx.x * blockDim.x + threadIdx.x;
    if (i >= n_links * DD) return;
    int l = i >> 5, d = i & 31;
    int b = loff[l], e = loff[l + 1];
    float s = 0.0f;
    for (int k = b; k < e; ++k) s += ps[(size_t)pbl[k] * DD + d];
    psum[i] = s;
}

// fused readout MLP: 32 -> 256 relu -> 256 relu -> 1, NP paths per 256-thread block
__global__ __launch_bounds__(256) void readout_kernel(
    const float* __restrict__ ps,
    const float* __restrict__ w1, const float* __restrict__ b1,
    const float* __restrict__ w2, const float* __restrict__ b2,
    const float* __restrict__ w3, const float* __restrict__ b3,
    float* __restrict__ out, int n_paths)
{
    __shared__ __align__(16) float xsh[NP * DD];
    __shared__ __align__(16) float h1[NP * 256];
    __shared__ float wred[4 * NP];
    int j = threadIdx.x;
    int p0 = blockIdx.x * NP;
    for (int i = j; i < NP * DD; i += 256){
        int p = p0 + i / DD;
        xsh[i] = (p < n_paths) ? ps[(size_t)p * DD + (i % DD)] : 0.0f;
    }
    __syncthreads();

    float acc[NP];
    float bj = b1[j];
    #pragma unroll
    for (int p = 0; p < NP; p++) acc[p] = bj;
    const float4* xq = (const float4*)xsh;
    #pragma unroll 1
    for (int k4 = 0; k4 < DD / 4; k4++){
        float wa = w1[(k4 * 4 + 0) * 256 + j];
        float wb = w1[(k4 * 4 + 1) * 256 + j];
        float wc = w1[(k4 * 4 + 2) * 256 + j];
        float wd = w1[(k4 * 4 + 3) * 256 + j];
        #pragma unroll
        for (int p = 0; p < NP; p++){
            float4 hv = xq[p * (DD / 4) + k4];
            acc[p] = fmaf(hv.x, wa, acc[p]);
            acc[p] = fmaf(hv.y, wb, acc[p]);
            acc[p] = fmaf(hv.z, wc, acc[p]);
            acc[p] = fmaf(hv.w, wd, acc[p]);
        }
    }
    #pragma unroll
    for (int p = 0; p < NP; p++) h1[p * 256 + j] = fmaxf(acc[p], 0.0f);
    __syncthreads();

    float b2j = b2[j];
    #pragma unroll
    for (int p = 0; p < NP; p++) acc[p] = b2j;
    const float4* h1q = (const float4*)h1;
    #pragma unroll 1
    for (int k4 = 0; k4 < 64; k4++){
        float wa = w2[(k4 * 4 + 0) * 256 + j];
        float wb = w2[(k4 * 4 + 1) * 256 + j];
        float wc = w2[(k4 * 4 + 2) * 256 + j];
        float wd = w2[(k4 * 4 + 3) * 256 + j];
        #pragma unroll
        for (int p = 0; p < NP; p++){
            float4 hv = h1q[p * 64 + k4];
            acc[p] = fmaf(hv.x, wa, acc[p]);
            acc[p] = fmaf(hv.y, wb, acc[p]);
            acc[p] = fmaf(hv.z, wc, acc[p]);
            acc[p] = fmaf(hv.w, wd, acc[p]);
        }
    }

    float w3j = w3[j];
    int lane = j & 63, wid = j >> 6;
    #pragma unroll
    for (int p = 0; p < NP; p++){
        float v = fmaxf(acc[p], 0.0f) * w3j;
        v += __shfl_down(v, 32);
        v += __shfl_down(v, 16);
        v += __shfl_down(v, 8);
        v += __shfl_down(v, 4);
        v += __shfl_down(v, 2);
        v += __shfl_down(v, 1);
        if (lane == 0) wred[wid * NP + p] = v;
    }
    __syncthreads();
    if (j < NP){
        int p = p0 + j;
        if (p < n_paths){
            float v = wred[j] + wred[NP + j] + wred[2 * NP + j] + wred[3 * NP + j] + b3[0];
            out[p] = v;
        }
    }
}

static int host_gcd(int a, int b){ while (b){ int t = a % b; a = b; b = t; } return a; }

extern "C" void kernel_launch(void* const* d_in, const int* in_sizes, int n_in,
                              void* d_out, int out_size, void* d_ws, size_t ws_size,
                              hipStream_t stream)
{
    const float* capacity = (const float*)d_in[0];
    const float* traffic  = (const float*)d_in[1];
    const float* packets  = (const float*)d_in[2];
    const float* tdp      = (const float*)d_in[3];
    const float* pK  = (const float*)d_in[4];
    const float* pRK = (const float*)d_in[5];
    const float* pB  = (const float*)d_in[6];
    const float* lK  = (const float*)d_in[7];
    const float* lRK = (const float*)d_in[8];
    const float* lB  = (const float*)d_in[9];
    const float* w1  = (const float*)d_in[10];
    const float* b1  = (const float*)d_in[11];
    const float* w2  = (const float*)d_in[12];
    const float* b2  = (const float*)d_in[13];
    const float* w3  = (const float*)d_in[14];
    const float* b3  = (const float*)d_in[15];
    const int* l2p      = (const int*)d_in[16];
    const int* path_ids = (const int*)d_in[17];
    const int* seqp     = (const int*)d_in[18];
    const int* p2l      = (const int*)d_in[19];
    const int* seql     = (const int*)d_in[20];
    int n_links = in_sizes[0];
    int n_paths = in_sizes[1];
    int E       = in_sizes[16];
    float* out = (float*)d_out;

    char* w = (char*)d_ws;
    auto carve = [&](size_t bytes) -> void* {
        void* r = (void*)w;
        w += (bytes + 255) & ~(size_t)255;
        return r;
    };
    float* ls    = (float*)carve((size_t)n_links * DD * 4);
    short* lsbh  = (short*)carve((size_t)n_links * DD * 2);
    short* lsbl  = (short*)carve((size_t)n_links * DD * 2);
    float* ps    = (float*)carve((size_t)n_paths * DD * 4);
    float* psum  = (float*)carve((size_t)n_links * DD * 4);
    int* start   = (int*)carve((size_t)n_paths * 4);
    int* lenp    = (int*)carve((size_t)n_paths * 4);
    int* order   = (int*)carve((size_t)n_paths * 4);
    int* loff    = (int*)carve((size_t)(n_links + 1) * 4);
    int* pbl     = (int*)carve((size_t)E * 4);
    int* izero   = (int*)carve(((size_t)2 * n_links + 48) * 4);
    int* lcount  = izero;
    int* lfill   = izero + n_links;
    int* bcnt    = izero + 2 * n_links;
    int* bfill   = izero + 2 * n_links + 16;
    int* bbase   = izero + 2 * n_links + 32;

    const int TB = 256;
    int nz = 2 * n_links + 48;
    zero_ints_kernel<<<(nz + TB - 1) / TB, TB, 0, stream>>>(izero, nz);
    init_link_kernel<<<(n_links * DD + TB - 1) / TB, TB, 0, stream>>>(capacity, ls, lsbh, lsbl, n_links);
    init_path_kernel<<<(n_paths * DD + TB - 1) / TB, TB, 0, stream>>>(traffic, packets, tdp, ps, n_paths);
    meta_kernel<<<(E + TB - 1) / TB, TB, 0, stream>>>(path_ids, seqp, seql, start, lenp, lcount, E);
    bhist_kernel<<<(n_paths + TB - 1) / TB, TB, 0, stream>>>(lenp, bcnt, n_paths);
    bscan_kernel<<<1, 64, 0, stream>>>(bcnt, bbase);
    bscatter_kernel<<<(n_paths + TB - 1) / TB, TB, 0, stream>>>(lenp, bbase, bfill, order, n_paths);
    scan_kernel<<<1, 1024, 0, stream>>>(lcount, loff, n_links);
    fillpbl_kernel<<<(E + TB - 1) / TB, TB, 0, stream>>>(seql, p2l, loff, lfill, pbl, E);

    int n_waves = (n_paths + 15) / 16;
    int stride = 1;
    if (n_waves > 2){
        stride = (int)((double)n_waves * 0.381966);
        if (stride < 1) stride = 1;
        while (host_gcd(stride, n_waves) != 1) stride++;
    }
    int pg_blocks = (n_waves + 3) / 4;
    int lg_blocks = ((n_links + 15) / 16 + 3) / 4;

    for (int it = 0; it < 8; ++it){
        path_gru_kernel<<<pg_blocks, 256, 0, stream>>>(lsbh, lsbl, ps, l2p, start, lenp, order,
                                                       pK, pRK, pB, n_paths, n_waves, stride);
        psum_kernel<<<(n_links * DD + TB - 1) / TB, TB, 0, stream>>>(ps, loff, pbl, psum, n_links);
        link_gru_kernel<<<lg_blocks, 256, 0, stream>>>(psum, ls, lsbh, lsbl, lK, lRK, lB, n_links);
    }
    readout_kernel<<<(n_paths + NP - 1) / NP, 256, 0, stream>>>(ps, w1, b1, w2, b2, w3, b3, out, n_paths);
}